// Round 15
// baseline (1246.292 us; speedup 1.0000x reference)
//
#include <hip/hip_runtime.h>
#include <hip/hip_fp16.h>
#include <math.h>

typedef _Float16 f16;
typedef _Float16 f16x2 __attribute__((ext_vector_type(2)));
typedef _Float16 f16x4 __attribute__((ext_vector_type(4)));
typedef _Float16 f16x8 __attribute__((ext_vector_type(8)));
typedef float f32x4 __attribute__((ext_vector_type(4)));
typedef unsigned long long u64;

// async global->LDS, 16B per lane; LDS dest must be wave-uniform base (HW adds lane*16)
#define GLD16(g, s) __builtin_amdgcn_global_load_lds( \
    (const __attribute__((address_space(1))) void*)(g), \
    (__attribute__((address_space(3))) void*)(s), 16, 0, 0)

// trunc+RNE split: hi = f16(x mantissa-truncated to 13 bits) [exact cast in
// range], lo = RNE(e - em). absmax ~4e-3 measured.
struct HL { f16 h, l; };
__device__ __forceinline__ HL split1(float e) {
  float em = __uint_as_float(__float_as_uint(e) & 0xFFFFE000u);
  HL r;
  r.h = (f16)em;
  r.l = (f16)(e - em);
  return r;
}

// pair-packed split via v_cvt_pkrtz: hi = pkrtz(trunc13(e)) [EXACT], lo =
// pkrtz(e - trunc13(e)) [RTZ residual]. r14-verified: 100% pipe-sum in gemm1.
__device__ __forceinline__ void splitcvt8(f32x4 u, f32x4 v, f16x8& H, f16x8& L) {
  union { f16x2 h2[4]; f16x8 h8; } uh, ul;
#pragma unroll
  for (int p = 0; p < 2; ++p) {
    float a = u[2 * p] * 256.0f, b = u[2 * p + 1] * 256.0f;
    float am = __uint_as_float(__float_as_uint(a) & 0xFFFFE000u);
    float bm = __uint_as_float(__float_as_uint(b) & 0xFFFFE000u);
    auto pk = __builtin_amdgcn_cvt_pkrtz(am, bm);          // exact
    uh.h2[p] = *reinterpret_cast<f16x2*>(&pk);
    auto pl = __builtin_amdgcn_cvt_pkrtz(a - am, b - bm);  // RTZ residual
    ul.h2[p] = *reinterpret_cast<f16x2*>(&pl);
  }
#pragma unroll
  for (int p = 0; p < 2; ++p) {
    float a = v[2 * p] * 256.0f, b = v[2 * p + 1] * 256.0f;
    float am = __uint_as_float(__float_as_uint(a) & 0xFFFFE000u);
    float bm = __uint_as_float(__float_as_uint(b) & 0xFFFFE000u);
    auto pk = __builtin_amdgcn_cvt_pkrtz(am, bm);
    uh.h2[2 + p] = *reinterpret_cast<f16x2*>(&pk);
    auto pl = __builtin_amdgcn_cvt_pkrtz(a - am, b - bm);
    ul.h2[2 + p] = *reinterpret_cast<f16x2*>(&pl);
  }
  H = uh.h8;
  L = ul.h8;
}

// ---------------------------------------------------------------------------
// split fp32 -> (hi, lo) f16 pair, pre-scaled by `scale` (=256). Weights only.
// ---------------------------------------------------------------------------
__global__ __launch_bounds__(256) void split_kernel(const float* __restrict__ src,
                                                    f16* __restrict__ hi,
                                                    f16* __restrict__ lo,
                                                    long n4, float scale) {
  long stride = (long)gridDim.x * blockDim.x;
  for (long i = (long)blockIdx.x * blockDim.x + threadIdx.x; i < n4; i += stride) {
    float4 v = ((const float4*)src)[i];
    f16x4 h, l;
    HL r0 = split1(v.x * scale); h[0] = r0.h; l[0] = r0.l;
    HL r1 = split1(v.y * scale); h[1] = r1.h; l[1] = r1.l;
    HL r2 = split1(v.z * scale); h[2] = r2.h; l[2] = r2.l;
    HL r3 = split1(v.w * scale); h[3] = r3.h; l[3] = r3.l;
    ((f16x4*)hi)[i] = h;
    ((f16x4*)lo)[i] = l;
  }
}

// ---------------------------------------------------------------------------
// gemm1: FUSED fp32-A split GEMM, 128x128 tile, BK=32, 4 waves (2x2),
// double-buffered LDS (64 KB -> 2 blocks/CU). r14-verified: 100% pipe-sum.
// ---------------------------------------------------------------------------
__global__ __launch_bounds__(256) void gemm1_128(
    const float* __restrict__ Af,
    const f16* __restrict__ B1, const f16* __restrict__ B2,
    const float* __restrict__ bias,
    f16* __restrict__ out1, f16* __restrict__ out2,
    const int M, const int K) {
  // per buffer: A fp32 128x32 = 16K | B1 8K | B2 8K = 32 KB
  __shared__ __align__(16) char smem[2][32768];
  const int tid = threadIdx.x;           // 0..255
  const int lane = tid & 63;
  const int wid = tid >> 6;              // 0..3
  const int wr = wid >> 1, wcol = wid & 1;
  const int m0 = blockIdx.y * 128;
  const int n0 = blockIdx.x * 128;

  f32x4 acc[4][4];
#pragma unroll
  for (int m = 0; m < 4; ++m)
#pragma unroll
    for (int n = 0; n < 4; ++n) acc[m][n] = (f32x4){0.f, 0.f, 0.f, 0.f};

  // A staging (r3-verified): fp32 128x32, chunk-XOR c^(row&7)
  const float* gAf[4];
#pragma unroll
  for (int q = 0; q < 4; ++q) {
    int rowg = m0 + q * 32 + (tid >> 3);
    if (rowg > M - 1) rowg = M - 1;
    const int chunkg = (tid & 7) ^ ((tid >> 3) & 7);
    gAf[q] = Af + (size_t)rowg * K + chunkg * 4;
  }
  // B staging (r2-verified f16 pattern, 0 conflicts)
  const int rq = tid >> 2;                                  // 0..63
  const int cg = (((tid & 3) ^ ((rq >> 1) & 3)) * 8);
  const f16* gB1q0 = B1 + (size_t)(n0 + rq) * K + cg;
  const f16* gB1q1 = B1 + (size_t)(n0 + 64 + rq) * K + cg;
  const f16* gB2q0 = B2 + (size_t)(n0 + rq) * K + cg;
  const f16* gB2q1 = B2 + (size_t)(n0 + 64 + rq) * K + cg;
  const int du = wid * 512;

  const int arow = wr * 64 + (lane & 15);
  const int brow = wcol * 64 + (lane & 15);
  const int kcB = (((lane >> 4) ^ ((brow >> 1) & 3)) * 8);
  const int pA0 = (((lane >> 4) * 2)     ^ (arow & 7)) * 4;
  const int pA1 = (((lane >> 4) * 2 + 1) ^ (arow & 7)) * 4;

  const int nt = K / 32;

#define STAGE(buf, kt)                                            \
  do {                                                            \
    char* smx_ = smem[buf];                                       \
    float* db = (float*)smx_;                                     \
    GLD16(gAf[0] + (kt), db + 0 * 1024 + wid * 256);              \
    GLD16(gAf[1] + (kt), db + 1 * 1024 + wid * 256);              \
    GLD16(gAf[2] + (kt), db + 2 * 1024 + wid * 256);              \
    GLD16(gAf[3] + (kt), db + 3 * 1024 + wid * 256);              \
    GLD16(gB1q0 + (kt), (f16*)(smx_ + 16384) + du);               \
    GLD16(gB1q1 + (kt), (f16*)(smx_ + 16384) + 2048 + du);        \
    GLD16(gB2q0 + (kt), (f16*)(smx_ + 24576) + du);               \
    GLD16(gB2q1 + (kt), (f16*)(smx_ + 24576) + 2048 + du);        \
  } while (0)

  STAGE(0, 0);

  for (int t = 0; t < nt; ++t) {
    asm volatile("s_waitcnt vmcnt(0)" ::: "memory");
    asm volatile("s_waitcnt lgkmcnt(0)" ::: "memory");
    __builtin_amdgcn_s_barrier();
    __builtin_amdgcn_sched_barrier(0);

    const char* smx = smem[t & 1];
    const float* sf = (const float*)smx;
    f16x8 a1[4], a2[4], b1[4], b2[4];
#pragma unroll
    for (int m = 0; m < 4; ++m) {
      const float* rp = sf + (arow + m * 16) * 32;
      f32x4 u = *(const f32x4*)(rp + pA0);
      f32x4 v = *(const f32x4*)(rp + pA1);
      splitcvt8(u, v, a1[m], a2[m]);
    }
    {
      const f16* sb1 = (const f16*)(smx + 16384);
      const f16* sb2 = (const f16*)(smx + 24576);
#pragma unroll
      for (int n = 0; n < 4; ++n) {
        b1[n] = *(const f16x8*)&sb1[(brow + n * 16) * 32 + kcB];
        b2[n] = *(const f16x8*)&sb2[(brow + n * 16) * 32 + kcB];
      }
    }

    if (t + 1 < nt) STAGE((t + 1) & 1, (t + 1) * 32);  // after reads of this buf

    // product-major: 16 independent MFMAs between dependent acc reuses
#pragma unroll
    for (int m = 0; m < 4; ++m)
#pragma unroll
      for (int n = 0; n < 4; ++n)
        acc[m][n] = __builtin_amdgcn_mfma_f32_16x16x32_f16(a1[m], b1[n], acc[m][n], 0, 0, 0);
#pragma unroll
    for (int m = 0; m < 4; ++m)
#pragma unroll
      for (int n = 0; n < 4; ++n)
        acc[m][n] = __builtin_amdgcn_mfma_f32_16x16x32_f16(a2[m], b1[n], acc[m][n], 0, 0, 0);
#pragma unroll
    for (int m = 0; m < 4; ++m)
#pragma unroll
      for (int n = 0; n < 4; ++n)
        acc[m][n] = __builtin_amdgcn_mfma_f32_16x16x32_f16(a1[m], b2[n], acc[m][n], 0, 0, 0);
  }
#undef STAGE

  const int crow = m0 + wr * 64 + 4 * (lane >> 4);
  const int ccol0 = n0 + wcol * 64 + (lane & 15);
#pragma unroll
  for (int n = 0; n < 4; ++n) {
    const int col = ccol0 + n * 16;
    const float bv = bias[col];
#pragma unroll
    for (int m = 0; m < 4; ++m) {
#pragma unroll
      for (int j = 0; j < 4; ++j) {
        const int row = crow + m * 16 + j;
        if (row < M) {
          float v = acc[m][n][j] * (1.0f / 65536.0f) + bv;
          v = fmaxf(v, 0.0f);
          HL r = split1(v * 256.0f);
          out1[(size_t)row * 1024 + col] = r.h;
          out2[(size_t)row * 1024 + col] = r.l;
        }
      }
    }
  }
}

// ---------------------------------------------------------------------------
// gemm2: pre-split f16 hi/lo GEMM (r12 path, 256x128 tile, tbuf, vmcnt(6)).
// ---------------------------------------------------------------------------
__global__ __launch_bounds__(512) void gemm2_k(
    const f16* __restrict__ A1, const f16* __restrict__ A2,
    const f16* __restrict__ B1, const f16* __restrict__ B2,
    const float* __restrict__ bias,
    float* __restrict__ out1,
    const int M, const int K) {
  __shared__ __align__(16) char smem[3][49152];
  const int tid = threadIdx.x;
  const int lane = tid & 63;
  const int wid = tid >> 6;
  const int wr = wid >> 1, wcol = wid & 1;
  const int m0 = blockIdx.y * 256;
  const int n0 = blockIdx.x * 128;

  f32x4 acc[4][4];
#pragma unroll
  for (int m = 0; m < 4; ++m)
#pragma unroll
    for (int n = 0; n < 4; ++n) acc[m][n] = (f32x4){0.f, 0.f, 0.f, 0.f};

  const int cg = (((tid & 3) ^ ((tid >> 3) & 3)) * 8);
  const f16* gB1 = B1 + (size_t)(n0 + (tid >> 2)) * K + cg;
  const f16* gB2 = B2 + (size_t)(n0 + (tid >> 2)) * K + cg;
  int ra0 = m0 + (tid >> 2);       if (ra0 > M - 1) ra0 = M - 1;
  int ra1 = m0 + 128 + (tid >> 2); if (ra1 > M - 1) ra1 = M - 1;
  const f16* gA1q0 = A1 + (size_t)ra0 * K + cg;
  const f16* gA1q1 = A1 + (size_t)ra1 * K + cg;
  const f16* gA2q0 = A2 + (size_t)ra0 * K + cg;
  const f16* gA2q1 = A2 + (size_t)ra1 * K + cg;

  const int arow = wr * 64 + (lane & 15);
  const int brow = wcol * 64 + (lane & 15);
  const int kcA = (((lane >> 4) ^ ((arow >> 1) & 3)) * 8);
  const int kcB = (((lane >> 4) ^ ((brow >> 1) & 3)) * 8);

  const int nt = K / 32;

#define STAGE(buf, kt)                                            \
  do {                                                            \
    char* smx_ = smem[buf];                                       \
    f16* d1 = (f16*)smx_;                                         \
    f16* d2 = d1 + 8192;                                          \
    GLD16(gA1q0 + (kt), d1 + wid * 512);                          \
    GLD16(gA1q1 + (kt), d1 + 4096 + wid * 512);                   \
    GLD16(gA2q0 + (kt), d2 + wid * 512);                          \
    GLD16(gA2q1 + (kt), d2 + 4096 + wid * 512);                   \
    GLD16(gB1 + (kt), (f16*)(smx_ + 32768) + wid * 512);          \
    GLD16(gB2 + (kt), (f16*)(smx_ + 40960) + wid * 512);          \
  } while (0)

  STAGE(0, 0);
  if (nt > 1) STAGE(1, 32);
  int cur = 0;

  for (int t = 0; t < nt; ++t) {
    if (t + 1 < nt) asm volatile("s_waitcnt vmcnt(6)" ::: "memory");
    else            asm volatile("s_waitcnt vmcnt(0)" ::: "memory");
    asm volatile("s_waitcnt lgkmcnt(0)" ::: "memory");
    __builtin_amdgcn_s_barrier();
    __builtin_amdgcn_sched_barrier(0);

    const char* smx = smem[cur];
    const f16* s1 = (const f16*)smx;
    const f16* s2 = s1 + 8192;
    const f16* sb1 = (const f16*)(smx + 32768);
    const f16* sb2 = (const f16*)(smx + 40960);
    f16x8 a1[4], a2[4], b1[4], b2[4];
#pragma unroll
    for (int m = 0; m < 4; ++m) {
      a1[m] = *(const f16x8*)&s1[(arow + m * 16) * 32 + kcA];
      a2[m] = *(const f16x8*)&s2[(arow + m * 16) * 32 + kcA];
    }
#pragma unroll
    for (int n = 0; n < 4; ++n) {
      b1[n] = *(const f16x8*)&sb1[(brow + n * 16) * 32 + kcB];
      b2[n] = *(const f16x8*)&sb2[(brow + n * 16) * 32 + kcB];
    }

    int pre = cur + 2; if (pre >= 3) pre -= 3;
    if (t + 2 < nt) STAGE(pre, (t + 2) * 32);

#pragma unroll
    for (int m = 0; m < 4; ++m)
#pragma unroll
      for (int n = 0; n < 4; ++n)
        acc[m][n] = __builtin_amdgcn_mfma_f32_16x16x32_f16(a1[m], b1[n], acc[m][n], 0, 0, 0);
#pragma unroll
    for (int m = 0; m < 4; ++m)
#pragma unroll
      for (int n = 0; n < 4; ++n)
        acc[m][n] = __builtin_amdgcn_mfma_f32_16x16x32_f16(a2[m], b1[n], acc[m][n], 0, 0, 0);
#pragma unroll
    for (int m = 0; m < 4; ++m)
#pragma unroll
      for (int n = 0; n < 4; ++n)
        acc[m][n] = __builtin_amdgcn_mfma_f32_16x16x32_f16(a1[m], b2[n], acc[m][n], 0, 0, 0);

    ++cur; if (cur >= 3) cur = 0;
  }
#undef STAGE

  const int crow = m0 + wr * 64 + 4 * (lane >> 4);
  const int ccol0 = n0 + wcol * 64 + (lane & 15);
#pragma unroll
  for (int n = 0; n < 4; ++n) {
    const int col = ccol0 + n * 16;
    const float bv = bias[col];
#pragma unroll
    for (int m = 0; m < 4; ++m) {
#pragma unroll
      for (int j = 0; j < 4; ++j) {
        const int row = crow + m * 16 + j;
        if (row < M) {
          float v = acc[m][n][j] * (1.0f / 65536.0f) + bv;
          out1[(size_t)row * 1024 + col] = fmaxf(v, 0.0f);
        }
      }
    }
  }
}

// ---------------------------------------------------------------------------
// Final head: c/r dots (fp32), argmax/scores, per-class delta, box decode+clip
// ---------------------------------------------------------------------------
__device__ __forceinline__ float dot4f(float4 a, float4 b) {
  return a.x * b.x + a.y * b.y + a.z * b.z + a.w * b.w;
}

__global__ __launch_bounds__(256) void head_final(
    const float* __restrict__ v7,
    const float* __restrict__ wc, const float* __restrict__ bc,
    const float* __restrict__ wr, const float* __restrict__ br,
    const float* __restrict__ rois,
    float* __restrict__ outScores, float* __restrict__ outClasses,
    float* __restrict__ outBoxes,
    float* __restrict__ smask, float* __restrict__ wsbox, int* __restrict__ wsval) {
  const int gw = (blockIdx.x * 256 + threadIdx.x) >> 6;
  const int lane = threadIdx.x & 63;
  if (gw >= 8000) return;

  const float4* vr = (const float4*)(v7 + (size_t)gw * 1024);
  float4 x0 = vr[lane], x1 = vr[64 + lane], x2 = vr[128 + lane], x3 = vr[192 + lane];

  float s[20];
#pragma unroll
  for (int o = 0; o < 20; ++o) {
    const float* wrow = (o < 4) ? (wc + o * 1024) : (wr + (o - 4) * 1024);
    const float4* w4 = (const float4*)wrow;
    float a = dot4f(x0, w4[lane]) + dot4f(x1, w4[64 + lane]) +
              dot4f(x2, w4[128 + lane]) + dot4f(x3, w4[192 + lane]);
#pragma unroll
    for (int off = 32; off >= 1; off >>= 1) a += __shfl_xor(a, off);
    s[o] = a + ((o < 4) ? bc[o] : br[o - 4]);
  }

  float best = s[0]; int cls = 0;
  if (s[1] > best) { best = s[1]; cls = 1; }
  if (s[2] > best) { best = s[2]; cls = 2; }
  if (s[3] > best) { best = s[3]; cls = 3; }

  float d0, d1, d2, d3;  // constant indices only (avoid scratch)
  if      (cls == 0) { d0 = s[4];  d1 = s[5];  d2 = s[6];  d3 = s[7];  }
  else if (cls == 1) { d0 = s[8];  d1 = s[9];  d2 = s[10]; d3 = s[11]; }
  else if (cls == 2) { d0 = s[12]; d1 = s[13]; d2 = s[14]; d3 = s[15]; }
  else               { d0 = s[16]; d1 = s[17]; d2 = s[18]; d3 = s[19]; }

  float4 rb = ((const float4*)rois)[gw];
  float w = rb.z - rb.x, h = rb.w - rb.y;
  float cx = rb.x + 0.5f * w, cy = rb.y + 0.5f * h;
  float pcx = cx + d0 * 0.1f * w;
  float pcy = cy + d1 * 0.1f * h;
  float pw = expf(d2 * 0.2f) * w;
  float ph = expf(d3 * 0.2f) * h;
  float bx0 = fminf(fmaxf(pcx - 0.5f * pw, 0.f), 512.f);
  float by0 = fminf(fmaxf(pcy - 0.5f * ph, 0.f), 512.f);
  float bx1 = fminf(fmaxf(pcx + 0.5f * pw, 0.f), 512.f);
  float by1 = fminf(fmaxf(pcy + 0.5f * ph, 0.f), 512.f);

  if (lane == 0) {
    outScores[gw] = best;
    outClasses[gw] = (float)cls;
    outBoxes[gw * 4 + 0] = bx0;
    outBoxes[gw * 4 + 1] = by0;
    outBoxes[gw * 4 + 2] = bx1;
    outBoxes[gw * 4 + 3] = by1;
    int valid = (cls != 3);
    smask[gw] = valid ? best : -INFINITY;
    wsval[gw] = valid;
    float4 bb; bb.x = bx0; bb.y = by0; bb.z = bx1; bb.w = by1;
    ((float4*)wsbox)[gw] = bb;
  }
}

// ---------------------------------------------------------------------------
// Stable descending rank; j-loop unrolled 4-wide (independent LDS loads).
// ---------------------------------------------------------------------------
__global__ __launch_bounds__(256) void rank_kernel(
    const float* __restrict__ smask, const float* __restrict__ bx,
    const int* __restrict__ valid,
    int* __restrict__ order, float* __restrict__ sboxes, int* __restrict__ svalid) {
  __shared__ __align__(16) float sS[8000];
  const int tid = threadIdx.x;
  for (int i = tid; i < 8000; i += 256) sS[i] = smask[i];
  __syncthreads();
  const int i = blockIdx.x * 256 + tid;
  if (i >= 8000) return;
  const float si = sS[i];
  int cnt = 0;
  const float4* s4p = (const float4*)sS;
  for (int j4 = 0; j4 < 2000; j4 += 4) {
    float4 sa = s4p[j4], sb = s4p[j4 + 1], sc = s4p[j4 + 2], sd = s4p[j4 + 3];
    int jb = j4 * 4;
    cnt += (sa.x > si) || (sa.x == si && (jb + 0) < i);
    cnt += (sa.y > si) || (sa.y == si && (jb + 1) < i);
    cnt += (sa.z > si) || (sa.z == si && (jb + 2) < i);
    cnt += (sa.w > si) || (sa.w == si && (jb + 3) < i);
    cnt += (sb.x > si) || (sb.x == si && (jb + 4) < i);
    cnt += (sb.y > si) || (sb.y == si && (jb + 5) < i);
    cnt += (sb.z > si) || (sb.z == si && (jb + 6) < i);
    cnt += (sb.w > si) || (sb.w == si && (jb + 7) < i);
    cnt += (sc.x > si) || (sc.x == si && (jb + 8) < i);
    cnt += (sc.y > si) || (sc.y == si && (jb + 9) < i);
    cnt += (sc.z > si) || (sc.z == si && (jb + 10) < i);
    cnt += (sc.w > si) || (sc.w == si && (jb + 11) < i);
    cnt += (sd.x > si) || (sd.x == si && (jb + 12) < i);
    cnt += (sd.y > si) || (sd.y == si && (jb + 13) < i);
    cnt += (sd.z > si) || (sd.z == si && (jb + 14) < i);
    cnt += (sd.w > si) || (sd.w == si && (jb + 15) < i);
  }
  order[cnt] = i;
  svalid[cnt] = valid[i];
  ((float4*)sboxes)[cnt] = ((const float4*)bx)[i];
}

// ---------------------------------------------------------------------------
// Suppression bitmask matrix, ROW-MAJOR M[ri*128+w] (coalesced OR-phase reads
// across threads). One (t,w) per wave, 4 waves/block.
// ---------------------------------------------------------------------------
__global__ __launch_bounds__(256) void iou_matrix(const float* __restrict__ sboxes,
                                                  u64* __restrict__ M,
                                                  u64* __restrict__ Mdiag,
                                                  const int* __restrict__ svalid) {
  const int t = blockIdx.y;
  const int w = blockIdx.x * 4 + (threadIdx.x >> 6);
  if (w < t || w >= 125) return;
  if (svalid[t * 64] == 0 || svalid[w * 64] == 0) return;
  const int lane = threadIdx.x & 63;
  const int ri = t * 64 + lane;
  float4 rb = ((const float4*)sboxes)[ri];
  const float ra = (rb.z - rb.x) * (rb.w - rb.y);
  const float4* cb = (const float4*)sboxes + w * 64;
  u64 bits = 0;
#pragma unroll 4
  for (int j = 0; j < 64; ++j) {
    float4 c = cb[j];
    float x1 = fmaxf(rb.x, c.x), y1 = fmaxf(rb.y, c.y);
    float x2 = fminf(rb.z, c.z), y2 = fminf(rb.w, c.w);
    float inter = fmaxf(x2 - x1, 0.f) * fmaxf(y2 - y1, 0.f);
    float ca = (c.z - c.x) * (c.w - c.y);
    float iou = inter / (ra + ca - inter + 1e-8f);
    int gc = w * 64 + j;
    if (iou > 0.2f && gc > ri) bits |= (1ULL << j);
  }
  M[(size_t)ri * 128 + w] = bits;
  if (w == t) Mdiag[(size_t)t * 64 + lane] = bits;
}

// ---------------------------------------------------------------------------
// Sequential greedy NMS scan. Per tile t: PREFETCH all 64 candidate rows of
// M into registers (independent of the closure -> closure hides L2 latency),
// run the ctz closure, then apply a branchless MASKED OR (rows[j] masked by
// kept bit j, fully unrolled -> static register indexing). Removes the
// post-closure dependent-load chain that serialized the old OR phase.
// ---------------------------------------------------------------------------
__global__ __launch_bounds__(128) void nms_scan(
    const u64* __restrict__ M, const u64* __restrict__ Mdiag,
    const int* __restrict__ order,
    const int* __restrict__ svalid, float* __restrict__ outKeep) {
  __shared__ __align__(16) u64 sMdiag[8000];   // 64 KB: 125 tiles x 64 rows
  __shared__ u64 acc[126];
  __shared__ u64 keptmask_s;
  __shared__ int tv[125];
  __shared__ int nvt_s;
  const int tid = threadIdx.x;
  for (int i = tid; i < 4000; i += 128)
    ((float4*)sMdiag)[i] = ((const float4*)Mdiag)[i];
  for (int w = tid; w < 125; w += 128) acc[w] = 0;
  if (tid < 125) tv[tid] = svalid[tid * 64];
  __syncthreads();
  if (tid == 0) {
    int c = 0;
    while (c < 125 && tv[c]) ++c;
    nvt_s = c;
  }
  __syncthreads();
  const int nvt = nvt_s;

  for (int t = 0; t < nvt; ++t) {
    const int w = t + 1 + tid;
    const bool act = (w < nvt);

    // --- prefetch all 64 candidate rows for this thread's column w ---
    u64 rows[64];
    if (act) {
      const u64* base = M + (size_t)t * 64 * 128 + w;
#pragma unroll
      for (int j = 0; j < 64; ++j) rows[j] = base[(size_t)j * 128];
    }

    // --- closure (wave 0), overlaps the prefetch latency ---
    if (tid < 64) {
      u64 myrow = sMdiag[t * 64 + tid];
      unsigned mlo = (unsigned)myrow, mhi = (unsigned)(myrow >> 32);
      u64 r = acc[t];
      u64 rem = ~r;                       // surviving candidates
      while (rem) {
        int i = __builtin_ctzll(rem);     // next kept box
        unsigned rlo = (unsigned)__builtin_amdgcn_readlane((int)mlo, i);
        unsigned rhi = (unsigned)__builtin_amdgcn_readlane((int)mhi, i);
        u64 rowi = ((u64)rhi << 32) | (u64)rlo;
        r |= rowi;
        rem &= ~(rowi | (1ULL << i));
      }
      if (tid == 0) { acc[t] = r; keptmask_s = ~r; }
    }
    __syncthreads();

    // --- branchless masked OR over prefetched rows ---
    if (act) {
      const u64 km = keptmask_s;
      u64 a = acc[w];
#pragma unroll
      for (int j = 0; j < 64; ++j)
        a |= rows[j] & (0ULL - ((km >> j) & 1ULL));
      acc[w] = a;
    }
    __syncthreads();
  }

  for (int p = tid; p < 8000; p += 128) {
    int removed = (int)((acc[p >> 6] >> (p & 63)) & 1ULL);
    float kv = (!removed && svalid[p]) ? 1.0f : 0.0f;
    outKeep[order[p]] = kv;
  }
}

// ---------------------------------------------------------------------------
extern "C" void kernel_launch(void* const* d_in, const int* in_sizes, int n_in,
                              void* d_out, int out_size, void* d_ws, size_t ws_size,
                              hipStream_t stream) {
  const float* F    = (const float*)d_in[0];
  const float* ROIS = (const float*)d_in[1];
  const float* W6   = (const float*)d_in[2];
  const float* B6   = (const float*)d_in[3];
  const float* W7   = (const float*)d_in[4];
  const float* B7   = (const float*)d_in[5];
  const float* WC   = (const float*)d_in[6];
  const float* BC   = (const float*)d_in[7];
  const float* WR   = (const float*)d_in[8];
  const float* BR   = (const float*)d_in[9];

  const size_t N = 8000, D = 12544, H = 1024;
  char* ws = (char*)d_ws;
  size_t off = 0;
  auto alloc = [&](size_t bytes) -> void* {
    void* p = (void*)(ws + off);
    off += (bytes + 255) & ~(size_t)255;
    return p;
  };
  f16*   B1w   = (f16*)alloc(H * D * 2);
  f16*   B2w   = (f16*)alloc(H * D * 2);
  f16*   V61   = (f16*)alloc(N * H * 2);
  f16*   V62   = (f16*)alloc(N * H * 2);
  f16*   W71   = (f16*)alloc(H * H * 2);
  f16*   W72   = (f16*)alloc(H * H * 2);
  float* V7    = (float*)alloc(N * H * 4);
  float* SMASK = (float*)alloc(N * 4);
  float* WSBOX = (float*)alloc(N * 16);
  int*   WSVAL = (int*)alloc(N * 4);
  int*   ORDER = (int*)alloc(N * 4);
  float* SBOX  = (float*)alloc(N * 16);
  int*   SVAL  = (int*)alloc(N * 4);
  u64*   MM    = (u64*)alloc(N * 128 * 8);
  u64*   MDIAG = (u64*)alloc(125 * 64 * 8);

  float* outScores  = (float*)d_out;
  float* outClasses = (float*)d_out + 8000;
  float* outBoxes   = (float*)d_out + 16000;
  float* outKeep    = (float*)d_out + 48000;

  split_kernel<<<1024, 256, 0, stream>>>(W6, B1w, B2w, (long)(H * D / 4), 256.0f);
  split_kernel<<<256, 256, 0, stream>>>(W7, W71, W72, (long)(H * H / 4), 256.0f);

  gemm1_128<<<dim3(8, 63), 256, 0, stream>>>(F, B1w, B2w, B6, V61, V62, 8000, 12544);
  gemm2_k<<<dim3(8, 32), 512, 0, stream>>>(V61, V62, W71, W72, B7, V7, 8000, 1024);

  head_final<<<2000, 256, 0, stream>>>(V7, WC, BC, WR, BR, ROIS,
                                       outScores, outClasses, outBoxes,
                                       SMASK, WSBOX, WSVAL);
  rank_kernel<<<32, 256, 0, stream>>>(SMASK, WSBOX, WSVAL, ORDER, SBOX, SVAL);
  iou_matrix<<<dim3(32, 125), 256, 0, stream>>>(SBOX, MM, MDIAG, SVAL);
  nms_scan<<<1, 128, 0, stream>>>(MM, MDIAG, ORDER, SVAL, outKeep);
}

// Round 16
// 941.835 us; speedup vs baseline: 1.3233x; 1.3233x over previous
//
#include <hip/hip_runtime.h>
#include <hip/hip_fp16.h>
#include <math.h>

typedef _Float16 f16;
typedef _Float16 f16x2 __attribute__((ext_vector_type(2)));
typedef _Float16 f16x4 __attribute__((ext_vector_type(4)));
typedef _Float16 f16x8 __attribute__((ext_vector_type(8)));
typedef float f32x4 __attribute__((ext_vector_type(4)));
typedef unsigned long long u64;

// async global->LDS, 16B per lane; LDS dest must be wave-uniform base (HW adds lane*16)
#define GLD16(g, s) __builtin_amdgcn_global_load_lds( \
    (const __attribute__((address_space(1))) void*)(g), \
    (__attribute__((address_space(3))) void*)(s), 16, 0, 0)

// trunc+RNE split: hi = f16(x mantissa-truncated to 13 bits) [exact cast in
// range], lo = RNE(e - em). absmax ~4e-3 measured.
struct HL { f16 h, l; };
__device__ __forceinline__ HL split1(float e) {
  float em = __uint_as_float(__float_as_uint(e) & 0xFFFFE000u);
  HL r;
  r.h = (f16)em;
  r.l = (f16)(e - em);
  return r;
}

// pair-packed split via v_cvt_pkrtz: hi = pkrtz(trunc13(e)) [EXACT], lo =
// pkrtz(e - trunc13(e)) [RTZ residual]. r14-verified: 100% pipe-sum in gemm1.
__device__ __forceinline__ void splitcvt8(f32x4 u, f32x4 v, f16x8& H, f16x8& L) {
  union { f16x2 h2[4]; f16x8 h8; } uh, ul;
#pragma unroll
  for (int p = 0; p < 2; ++p) {
    float a = u[2 * p] * 256.0f, b = u[2 * p + 1] * 256.0f;
    float am = __uint_as_float(__float_as_uint(a) & 0xFFFFE000u);
    float bm = __uint_as_float(__float_as_uint(b) & 0xFFFFE000u);
    auto pk = __builtin_amdgcn_cvt_pkrtz(am, bm);          // exact
    uh.h2[p] = *reinterpret_cast<f16x2*>(&pk);
    auto pl = __builtin_amdgcn_cvt_pkrtz(a - am, b - bm);  // RTZ residual
    ul.h2[p] = *reinterpret_cast<f16x2*>(&pl);
  }
#pragma unroll
  for (int p = 0; p < 2; ++p) {
    float a = v[2 * p] * 256.0f, b = v[2 * p + 1] * 256.0f;
    float am = __uint_as_float(__float_as_uint(a) & 0xFFFFE000u);
    float bm = __uint_as_float(__float_as_uint(b) & 0xFFFFE000u);
    auto pk = __builtin_amdgcn_cvt_pkrtz(am, bm);
    uh.h2[2 + p] = *reinterpret_cast<f16x2*>(&pk);
    auto pl = __builtin_amdgcn_cvt_pkrtz(a - am, b - bm);
    ul.h2[2 + p] = *reinterpret_cast<f16x2*>(&pl);
  }
  H = uh.h8;
  L = ul.h8;
}

// ---------------------------------------------------------------------------
// split fp32 -> (hi, lo) f16 pair, pre-scaled by `scale` (=256). Weights only.
// ---------------------------------------------------------------------------
__global__ __launch_bounds__(256) void split_kernel(const float* __restrict__ src,
                                                    f16* __restrict__ hi,
                                                    f16* __restrict__ lo,
                                                    long n4, float scale) {
  long stride = (long)gridDim.x * blockDim.x;
  for (long i = (long)blockIdx.x * blockDim.x + threadIdx.x; i < n4; i += stride) {
    float4 v = ((const float4*)src)[i];
    f16x4 h, l;
    HL r0 = split1(v.x * scale); h[0] = r0.h; l[0] = r0.l;
    HL r1 = split1(v.y * scale); h[1] = r1.h; l[1] = r1.l;
    HL r2 = split1(v.z * scale); h[2] = r2.h; l[2] = r2.l;
    HL r3 = split1(v.w * scale); h[3] = r3.h; l[3] = r3.l;
    ((f16x4*)hi)[i] = h;
    ((f16x4*)lo)[i] = l;
  }
}

// ---------------------------------------------------------------------------
// gemm1: FUSED fp32-A split GEMM, 128x128 tile, BK=32, 4 waves (2x2),
// double-buffered LDS (64 KB -> 2 blocks/CU). r14-verified: 100% pipe-sum.
// ---------------------------------------------------------------------------
__global__ __launch_bounds__(256) void gemm1_128(
    const float* __restrict__ Af,
    const f16* __restrict__ B1, const f16* __restrict__ B2,
    const float* __restrict__ bias,
    f16* __restrict__ out1, f16* __restrict__ out2,
    const int M, const int K) {
  // per buffer: A fp32 128x32 = 16K | B1 8K | B2 8K = 32 KB
  __shared__ __align__(16) char smem[2][32768];
  const int tid = threadIdx.x;           // 0..255
  const int lane = tid & 63;
  const int wid = tid >> 6;              // 0..3
  const int wr = wid >> 1, wcol = wid & 1;
  const int m0 = blockIdx.y * 128;
  const int n0 = blockIdx.x * 128;

  f32x4 acc[4][4];
#pragma unroll
  for (int m = 0; m < 4; ++m)
#pragma unroll
    for (int n = 0; n < 4; ++n) acc[m][n] = (f32x4){0.f, 0.f, 0.f, 0.f};

  // A staging (r3-verified): fp32 128x32, chunk-XOR c^(row&7)
  const float* gAf[4];
#pragma unroll
  for (int q = 0; q < 4; ++q) {
    int rowg = m0 + q * 32 + (tid >> 3);
    if (rowg > M - 1) rowg = M - 1;
    const int chunkg = (tid & 7) ^ ((tid >> 3) & 7);
    gAf[q] = Af + (size_t)rowg * K + chunkg * 4;
  }
  // B staging (r2-verified f16 pattern, 0 conflicts)
  const int rq = tid >> 2;                                  // 0..63
  const int cg = (((tid & 3) ^ ((rq >> 1) & 3)) * 8);
  const f16* gB1q0 = B1 + (size_t)(n0 + rq) * K + cg;
  const f16* gB1q1 = B1 + (size_t)(n0 + 64 + rq) * K + cg;
  const f16* gB2q0 = B2 + (size_t)(n0 + rq) * K + cg;
  const f16* gB2q1 = B2 + (size_t)(n0 + 64 + rq) * K + cg;
  const int du = wid * 512;

  const int arow = wr * 64 + (lane & 15);
  const int brow = wcol * 64 + (lane & 15);
  const int kcB = (((lane >> 4) ^ ((brow >> 1) & 3)) * 8);
  const int pA0 = (((lane >> 4) * 2)     ^ (arow & 7)) * 4;
  const int pA1 = (((lane >> 4) * 2 + 1) ^ (arow & 7)) * 4;

  const int nt = K / 32;

#define STAGE(buf, kt)                                            \
  do {                                                            \
    char* smx_ = smem[buf];                                       \
    float* db = (float*)smx_;                                     \
    GLD16(gAf[0] + (kt), db + 0 * 1024 + wid * 256);              \
    GLD16(gAf[1] + (kt), db + 1 * 1024 + wid * 256);              \
    GLD16(gAf[2] + (kt), db + 2 * 1024 + wid * 256);              \
    GLD16(gAf[3] + (kt), db + 3 * 1024 + wid * 256);              \
    GLD16(gB1q0 + (kt), (f16*)(smx_ + 16384) + du);               \
    GLD16(gB1q1 + (kt), (f16*)(smx_ + 16384) + 2048 + du);        \
    GLD16(gB2q0 + (kt), (f16*)(smx_ + 24576) + du);               \
    GLD16(gB2q1 + (kt), (f16*)(smx_ + 24576) + 2048 + du);        \
  } while (0)

  STAGE(0, 0);

  for (int t = 0; t < nt; ++t) {
    asm volatile("s_waitcnt vmcnt(0)" ::: "memory");
    asm volatile("s_waitcnt lgkmcnt(0)" ::: "memory");
    __builtin_amdgcn_s_barrier();
    __builtin_amdgcn_sched_barrier(0);

    const char* smx = smem[t & 1];
    const float* sf = (const float*)smx;
    f16x8 a1[4], a2[4], b1[4], b2[4];
#pragma unroll
    for (int m = 0; m < 4; ++m) {
      const float* rp = sf + (arow + m * 16) * 32;
      f32x4 u = *(const f32x4*)(rp + pA0);
      f32x4 v = *(const f32x4*)(rp + pA1);
      splitcvt8(u, v, a1[m], a2[m]);
    }
    {
      const f16* sb1 = (const f16*)(smx + 16384);
      const f16* sb2 = (const f16*)(smx + 24576);
#pragma unroll
      for (int n = 0; n < 4; ++n) {
        b1[n] = *(const f16x8*)&sb1[(brow + n * 16) * 32 + kcB];
        b2[n] = *(const f16x8*)&sb2[(brow + n * 16) * 32 + kcB];
      }
    }

    if (t + 1 < nt) STAGE((t + 1) & 1, (t + 1) * 32);  // after reads of this buf

    // product-major: 16 independent MFMAs between dependent acc reuses
#pragma unroll
    for (int m = 0; m < 4; ++m)
#pragma unroll
      for (int n = 0; n < 4; ++n)
        acc[m][n] = __builtin_amdgcn_mfma_f32_16x16x32_f16(a1[m], b1[n], acc[m][n], 0, 0, 0);
#pragma unroll
    for (int m = 0; m < 4; ++m)
#pragma unroll
      for (int n = 0; n < 4; ++n)
        acc[m][n] = __builtin_amdgcn_mfma_f32_16x16x32_f16(a2[m], b1[n], acc[m][n], 0, 0, 0);
#pragma unroll
    for (int m = 0; m < 4; ++m)
#pragma unroll
      for (int n = 0; n < 4; ++n)
        acc[m][n] = __builtin_amdgcn_mfma_f32_16x16x32_f16(a1[m], b2[n], acc[m][n], 0, 0, 0);
  }
#undef STAGE

  const int crow = m0 + wr * 64 + 4 * (lane >> 4);
  const int ccol0 = n0 + wcol * 64 + (lane & 15);
#pragma unroll
  for (int n = 0; n < 4; ++n) {
    const int col = ccol0 + n * 16;
    const float bv = bias[col];
#pragma unroll
    for (int m = 0; m < 4; ++m) {
#pragma unroll
      for (int j = 0; j < 4; ++j) {
        const int row = crow + m * 16 + j;
        if (row < M) {
          float v = acc[m][n][j] * (1.0f / 65536.0f) + bv;
          v = fmaxf(v, 0.0f);
          HL r = split1(v * 256.0f);
          out1[(size_t)row * 1024 + col] = r.h;
          out2[(size_t)row * 1024 + col] = r.l;
        }
      }
    }
  }
}

// ---------------------------------------------------------------------------
// gemm2: pre-split f16 hi/lo GEMM (r12 path, 256x128 tile, tbuf, vmcnt(6)).
// ---------------------------------------------------------------------------
__global__ __launch_bounds__(512) void gemm2_k(
    const f16* __restrict__ A1, const f16* __restrict__ A2,
    const f16* __restrict__ B1, const f16* __restrict__ B2,
    const float* __restrict__ bias,
    float* __restrict__ out1,
    const int M, const int K) {
  __shared__ __align__(16) char smem[3][49152];
  const int tid = threadIdx.x;
  const int lane = tid & 63;
  const int wid = tid >> 6;
  const int wr = wid >> 1, wcol = wid & 1;
  const int m0 = blockIdx.y * 256;
  const int n0 = blockIdx.x * 128;

  f32x4 acc[4][4];
#pragma unroll
  for (int m = 0; m < 4; ++m)
#pragma unroll
    for (int n = 0; n < 4; ++n) acc[m][n] = (f32x4){0.f, 0.f, 0.f, 0.f};

  const int cg = (((tid & 3) ^ ((tid >> 3) & 3)) * 8);
  const f16* gB1 = B1 + (size_t)(n0 + (tid >> 2)) * K + cg;
  const f16* gB2 = B2 + (size_t)(n0 + (tid >> 2)) * K + cg;
  int ra0 = m0 + (tid >> 2);       if (ra0 > M - 1) ra0 = M - 1;
  int ra1 = m0 + 128 + (tid >> 2); if (ra1 > M - 1) ra1 = M - 1;
  const f16* gA1q0 = A1 + (size_t)ra0 * K + cg;
  const f16* gA1q1 = A1 + (size_t)ra1 * K + cg;
  const f16* gA2q0 = A2 + (size_t)ra0 * K + cg;
  const f16* gA2q1 = A2 + (size_t)ra1 * K + cg;

  const int arow = wr * 64 + (lane & 15);
  const int brow = wcol * 64 + (lane & 15);
  const int kcA = (((lane >> 4) ^ ((arow >> 1) & 3)) * 8);
  const int kcB = (((lane >> 4) ^ ((brow >> 1) & 3)) * 8);

  const int nt = K / 32;

#define STAGE(buf, kt)                                            \
  do {                                                            \
    char* smx_ = smem[buf];                                       \
    f16* d1 = (f16*)smx_;                                         \
    f16* d2 = d1 + 8192;                                          \
    GLD16(gA1q0 + (kt), d1 + wid * 512);                          \
    GLD16(gA1q1 + (kt), d1 + 4096 + wid * 512);                   \
    GLD16(gA2q0 + (kt), d2 + wid * 512);                          \
    GLD16(gA2q1 + (kt), d2 + 4096 + wid * 512);                   \
    GLD16(gB1 + (kt), (f16*)(smx_ + 32768) + wid * 512);          \
    GLD16(gB2 + (kt), (f16*)(smx_ + 40960) + wid * 512);          \
  } while (0)

  STAGE(0, 0);
  if (nt > 1) STAGE(1, 32);
  int cur = 0;

  for (int t = 0; t < nt; ++t) {
    if (t + 1 < nt) asm volatile("s_waitcnt vmcnt(6)" ::: "memory");
    else            asm volatile("s_waitcnt vmcnt(0)" ::: "memory");
    asm volatile("s_waitcnt lgkmcnt(0)" ::: "memory");
    __builtin_amdgcn_s_barrier();
    __builtin_amdgcn_sched_barrier(0);

    const char* smx = smem[cur];
    const f16* s1 = (const f16*)smx;
    const f16* s2 = s1 + 8192;
    const f16* sb1 = (const f16*)(smx + 32768);
    const f16* sb2 = (const f16*)(smx + 40960);
    f16x8 a1[4], a2[4], b1[4], b2[4];
#pragma unroll
    for (int m = 0; m < 4; ++m) {
      a1[m] = *(const f16x8*)&s1[(arow + m * 16) * 32 + kcA];
      a2[m] = *(const f16x8*)&s2[(arow + m * 16) * 32 + kcA];
    }
#pragma unroll
    for (int n = 0; n < 4; ++n) {
      b1[n] = *(const f16x8*)&sb1[(brow + n * 16) * 32 + kcB];
      b2[n] = *(const f16x8*)&sb2[(brow + n * 16) * 32 + kcB];
    }

    int pre = cur + 2; if (pre >= 3) pre -= 3;
    if (t + 2 < nt) STAGE(pre, (t + 2) * 32);

#pragma unroll
    for (int m = 0; m < 4; ++m)
#pragma unroll
      for (int n = 0; n < 4; ++n)
        acc[m][n] = __builtin_amdgcn_mfma_f32_16x16x32_f16(a1[m], b1[n], acc[m][n], 0, 0, 0);
#pragma unroll
    for (int m = 0; m < 4; ++m)
#pragma unroll
      for (int n = 0; n < 4; ++n)
        acc[m][n] = __builtin_amdgcn_mfma_f32_16x16x32_f16(a2[m], b1[n], acc[m][n], 0, 0, 0);
#pragma unroll
    for (int m = 0; m < 4; ++m)
#pragma unroll
      for (int n = 0; n < 4; ++n)
        acc[m][n] = __builtin_amdgcn_mfma_f32_16x16x32_f16(a1[m], b2[n], acc[m][n], 0, 0, 0);

    ++cur; if (cur >= 3) cur = 0;
  }
#undef STAGE

  const int crow = m0 + wr * 64 + 4 * (lane >> 4);
  const int ccol0 = n0 + wcol * 64 + (lane & 15);
#pragma unroll
  for (int n = 0; n < 4; ++n) {
    const int col = ccol0 + n * 16;
    const float bv = bias[col];
#pragma unroll
    for (int m = 0; m < 4; ++m) {
#pragma unroll
      for (int j = 0; j < 4; ++j) {
        const int row = crow + m * 16 + j;
        if (row < M) {
          float v = acc[m][n][j] * (1.0f / 65536.0f) + bv;
          out1[(size_t)row * 1024 + col] = fmaxf(v, 0.0f);
        }
      }
    }
  }
}

// ---------------------------------------------------------------------------
// Final head: c/r dots (fp32), argmax/scores, per-class delta, box decode+clip
// ---------------------------------------------------------------------------
__device__ __forceinline__ float dot4f(float4 a, float4 b) {
  return a.x * b.x + a.y * b.y + a.z * b.z + a.w * b.w;
}

__global__ __launch_bounds__(256) void head_final(
    const float* __restrict__ v7,
    const float* __restrict__ wc, const float* __restrict__ bc,
    const float* __restrict__ wr, const float* __restrict__ br,
    const float* __restrict__ rois,
    float* __restrict__ outScores, float* __restrict__ outClasses,
    float* __restrict__ outBoxes,
    float* __restrict__ smask, float* __restrict__ wsbox, int* __restrict__ wsval) {
  const int gw = (blockIdx.x * 256 + threadIdx.x) >> 6;
  const int lane = threadIdx.x & 63;
  if (gw >= 8000) return;

  const float4* vr = (const float4*)(v7 + (size_t)gw * 1024);
  float4 x0 = vr[lane], x1 = vr[64 + lane], x2 = vr[128 + lane], x3 = vr[192 + lane];

  float s[20];
#pragma unroll
  for (int o = 0; o < 20; ++o) {
    const float* wrow = (o < 4) ? (wc + o * 1024) : (wr + (o - 4) * 1024);
    const float4* w4 = (const float4*)wrow;
    float a = dot4f(x0, w4[lane]) + dot4f(x1, w4[64 + lane]) +
              dot4f(x2, w4[128 + lane]) + dot4f(x3, w4[192 + lane]);
#pragma unroll
    for (int off = 32; off >= 1; off >>= 1) a += __shfl_xor(a, off);
    s[o] = a + ((o < 4) ? bc[o] : br[o - 4]);
  }

  float best = s[0]; int cls = 0;
  if (s[1] > best) { best = s[1]; cls = 1; }
  if (s[2] > best) { best = s[2]; cls = 2; }
  if (s[3] > best) { best = s[3]; cls = 3; }

  float d0, d1, d2, d3;  // constant indices only (avoid scratch)
  if      (cls == 0) { d0 = s[4];  d1 = s[5];  d2 = s[6];  d3 = s[7];  }
  else if (cls == 1) { d0 = s[8];  d1 = s[9];  d2 = s[10]; d3 = s[11]; }
  else if (cls == 2) { d0 = s[12]; d1 = s[13]; d2 = s[14]; d3 = s[15]; }
  else               { d0 = s[16]; d1 = s[17]; d2 = s[18]; d3 = s[19]; }

  float4 rb = ((const float4*)rois)[gw];
  float w = rb.z - rb.x, h = rb.w - rb.y;
  float cx = rb.x + 0.5f * w, cy = rb.y + 0.5f * h;
  float pcx = cx + d0 * 0.1f * w;
  float pcy = cy + d1 * 0.1f * h;
  float pw = expf(d2 * 0.2f) * w;
  float ph = expf(d3 * 0.2f) * h;
  float bx0 = fminf(fmaxf(pcx - 0.5f * pw, 0.f), 512.f);
  float by0 = fminf(fmaxf(pcy - 0.5f * ph, 0.f), 512.f);
  float bx1 = fminf(fmaxf(pcx + 0.5f * pw, 0.f), 512.f);
  float by1 = fminf(fmaxf(pcy + 0.5f * ph, 0.f), 512.f);

  if (lane == 0) {
    outScores[gw] = best;
    outClasses[gw] = (float)cls;
    outBoxes[gw * 4 + 0] = bx0;
    outBoxes[gw * 4 + 1] = by0;
    outBoxes[gw * 4 + 2] = bx1;
    outBoxes[gw * 4 + 3] = by1;
    int valid = (cls != 3);
    smask[gw] = valid ? best : -INFINITY;
    wsval[gw] = valid;
    float4 bb; bb.x = bx0; bb.y = by0; bb.z = bx1; bb.w = by1;
    ((float4*)wsbox)[gw] = bb;
  }
}

// ---------------------------------------------------------------------------
// Stable descending rank, ONE WAVE PER ROW i (2000 blocks x 4 waves = 8000
// waves; was 8000 threads at 1 wave/SIMD with zero latency hiding). Lane l
// sums j = k*64+l (stride-64: conflict-free), then 6-step shfl reduce.
// ---------------------------------------------------------------------------
__global__ __launch_bounds__(256) void rank_kernel(
    const float* __restrict__ smask, const float* __restrict__ bx,
    const int* __restrict__ valid,
    int* __restrict__ order, float* __restrict__ sboxes, int* __restrict__ svalid) {
  __shared__ __align__(16) float sS[8000];
  const int tid = threadIdx.x;
  for (int i = tid; i < 2000; i += 256)
    ((float4*)sS)[i] = ((const float4*)smask)[i];
  __syncthreads();
  const int i = blockIdx.x * 4 + (tid >> 6);   // this wave's row
  const int lane = tid & 63;
  const float si = sS[i];
  int cnt = 0;
#pragma unroll 5
  for (int k = 0; k < 125; ++k) {
    const int j = k * 64 + lane;
    const float sj = sS[j];
    cnt += (sj > si) || (sj == si && j < i);
  }
#pragma unroll
  for (int off = 32; off >= 1; off >>= 1) cnt += __shfl_xor(cnt, off);
  if (lane == 0) {
    order[cnt] = i;
    svalid[cnt] = valid[i];
    ((float4*)sboxes)[cnt] = ((const float4*)bx)[i];
  }
}

// ---------------------------------------------------------------------------
// Suppression bitmask matrix, ROW-MAJOR M[ri*128+w] (coalesced OR-phase reads
// across threads). One (t,w) per wave, 4 waves/block.
// ---------------------------------------------------------------------------
__global__ __launch_bounds__(256) void iou_matrix(const float* __restrict__ sboxes,
                                                  u64* __restrict__ M,
                                                  u64* __restrict__ Mdiag,
                                                  const int* __restrict__ svalid) {
  const int t = blockIdx.y;
  const int w = blockIdx.x * 4 + (threadIdx.x >> 6);
  if (w < t || w >= 125) return;
  if (svalid[t * 64] == 0 || svalid[w * 64] == 0) return;
  const int lane = threadIdx.x & 63;
  const int ri = t * 64 + lane;
  float4 rb = ((const float4*)sboxes)[ri];
  const float ra = (rb.z - rb.x) * (rb.w - rb.y);
  const float4* cb = (const float4*)sboxes + w * 64;
  u64 bits = 0;
#pragma unroll 4
  for (int j = 0; j < 64; ++j) {
    float4 c = cb[j];
    float x1 = fmaxf(rb.x, c.x), y1 = fmaxf(rb.y, c.y);
    float x2 = fminf(rb.z, c.z), y2 = fminf(rb.w, c.w);
    float inter = fmaxf(x2 - x1, 0.f) * fmaxf(y2 - y1, 0.f);
    float ca = (c.z - c.x) * (c.w - c.y);
    float iou = inter / (ra + ca - inter + 1e-8f);
    int gc = w * 64 + j;
    if (iou > 0.2f && gc > ri) bits |= (1ULL << j);
  }
  M[(size_t)ri * 128 + w] = bits;
  if (w == t) Mdiag[(size_t)t * 64 + lane] = bits;
}

// ---------------------------------------------------------------------------
// Sequential greedy NMS scan (r14-verified version). Mdiag staged in LDS,
// ctz closure over kept boxes, klist + batch-16 OR over row-major M.
// ---------------------------------------------------------------------------
__global__ __launch_bounds__(128) void nms_scan(
    const u64* __restrict__ M, const u64* __restrict__ Mdiag,
    const int* __restrict__ order,
    const int* __restrict__ svalid, float* __restrict__ outKeep) {
  __shared__ __align__(16) u64 sMdiag[8000];   // 64 KB: 125 tiles x 64 rows
  __shared__ u64 acc[126];
  __shared__ unsigned char klist[64];
  __shared__ int kcount;
  __shared__ int tv[125];
  __shared__ int nvt_s;
  const int tid = threadIdx.x;
  for (int i = tid; i < 4000; i += 128)
    ((float4*)sMdiag)[i] = ((const float4*)Mdiag)[i];
  for (int w = tid; w < 125; w += 128) acc[w] = 0;
  if (tid < 125) tv[tid] = svalid[tid * 64];
  __syncthreads();
  if (tid == 0) {
    int c = 0;
    while (c < 125 && tv[c]) ++c;
    nvt_s = c;
  }
  __syncthreads();
  const int nvt = nvt_s;

  for (int t = 0; t < nvt; ++t) {
    if (tid < 64) {  // wave 0: ctz closure over kept boxes
      u64 myrow = sMdiag[t * 64 + tid];
      unsigned mlo = (unsigned)myrow, mhi = (unsigned)(myrow >> 32);
      u64 r = acc[t];
      u64 rem = ~r;                       // surviving candidates
      while (rem) {
        int i = __builtin_ctzll(rem);     // next kept box
        unsigned rlo = (unsigned)__builtin_amdgcn_readlane((int)mlo, i);
        unsigned rhi = (unsigned)__builtin_amdgcn_readlane((int)mhi, i);
        u64 rowi = ((u64)rhi << 32) | (u64)rlo;
        r |= rowi;
        rem &= ~(rowi | (1ULL << i));
      }
      u64 kept = ~r;
      if (tid == 0) { acc[t] = r; kcount = (int)__popcll(kept); }
      if ((kept >> tid) & 1ULL)
        klist[__popcll(kept & ((1ULL << tid) - 1ULL))] = (unsigned char)tid;
    }
    __syncthreads();
    const int kc = kcount;
    const int w = t + 1 + tid;
    if (w < nvt) {
      u64 a = acc[w];
      const u64* base = M + (size_t)t * 64 * 128 + w;
      int j = 0;
      for (; j + 16 <= kc; j += 16) {   // 16 outstanding loads
        u64 o = 0;
#pragma unroll
        for (int q = 0; q < 16; ++q) o |= base[(size_t)klist[j + q] * 128];
        a |= o;
      }
      for (; j + 4 <= kc; j += 4) {
        u64 v0 = base[(size_t)klist[j] * 128];
        u64 v1 = base[(size_t)klist[j + 1] * 128];
        u64 v2 = base[(size_t)klist[j + 2] * 128];
        u64 v3 = base[(size_t)klist[j + 3] * 128];
        a |= (v0 | v1) | (v2 | v3);
      }
      for (; j < kc; ++j) a |= base[(size_t)klist[j] * 128];
      acc[w] = a;
    }
    __syncthreads();
  }

  for (int p = tid; p < 8000; p += 128) {
    int removed = (int)((acc[p >> 6] >> (p & 63)) & 1ULL);
    float kv = (!removed && svalid[p]) ? 1.0f : 0.0f;
    outKeep[order[p]] = kv;
  }
}

// ---------------------------------------------------------------------------
extern "C" void kernel_launch(void* const* d_in, const int* in_sizes, int n_in,
                              void* d_out, int out_size, void* d_ws, size_t ws_size,
                              hipStream_t stream) {
  const float* F    = (const float*)d_in[0];
  const float* ROIS = (const float*)d_in[1];
  const float* W6   = (const float*)d_in[2];
  const float* B6   = (const float*)d_in[3];
  const float* W7   = (const float*)d_in[4];
  const float* B7   = (const float*)d_in[5];
  const float* WC   = (const float*)d_in[6];
  const float* BC   = (const float*)d_in[7];
  const float* WR   = (const float*)d_in[8];
  const float* BR   = (const float*)d_in[9];

  const size_t N = 8000, D = 12544, H = 1024;
  char* ws = (char*)d_ws;
  size_t off = 0;
  auto alloc = [&](size_t bytes) -> void* {
    void* p = (void*)(ws + off);
    off += (bytes + 255) & ~(size_t)255;
    return p;
  };
  f16*   B1w   = (f16*)alloc(H * D * 2);
  f16*   B2w   = (f16*)alloc(H * D * 2);
  f16*   V61   = (f16*)alloc(N * H * 2);
  f16*   V62   = (f16*)alloc(N * H * 2);
  f16*   W71   = (f16*)alloc(H * H * 2);
  f16*   W72   = (f16*)alloc(H * H * 2);
  float* V7    = (float*)alloc(N * H * 4);
  float* SMASK = (float*)alloc(N * 4);
  float* WSBOX = (float*)alloc(N * 16);
  int*   WSVAL = (int*)alloc(N * 4);
  int*   ORDER = (int*)alloc(N * 4);
  float* SBOX  = (float*)alloc(N * 16);
  int*   SVAL  = (int*)alloc(N * 4);
  u64*   MM    = (u64*)alloc(N * 128 * 8);
  u64*   MDIAG = (u64*)alloc(125 * 64 * 8);

  float* outScores  = (float*)d_out;
  float* outClasses = (float*)d_out + 8000;
  float* outBoxes   = (float*)d_out + 16000;
  float* outKeep    = (float*)d_out + 48000;

  split_kernel<<<1024, 256, 0, stream>>>(W6, B1w, B2w, (long)(H * D / 4), 256.0f);
  split_kernel<<<256, 256, 0, stream>>>(W7, W71, W72, (long)(H * H / 4), 256.0f);

  gemm1_128<<<dim3(8, 63), 256, 0, stream>>>(F, B1w, B2w, B6, V61, V62, 8000, 12544);
  gemm2_k<<<dim3(8, 32), 512, 0, stream>>>(V61, V62, W71, W72, B7, V7, 8000, 1024);

  head_final<<<2000, 256, 0, stream>>>(V7, WC, BC, WR, BR, ROIS,
                                       outScores, outClasses, outBoxes,
                                       SMASK, WSBOX, WSVAL);
  rank_kernel<<<2000, 256, 0, stream>>>(SMASK, WSBOX, WSVAL, ORDER, SBOX, SVAL);
  iou_matrix<<<dim3(32, 125), 256, 0, stream>>>(SBOX, MM, MDIAG, SVAL);
  nms_scan<<<1, 128, 0, stream>>>(MM, MDIAG, ORDER, SVAL, outKeep);
}

// Round 17
// 938.645 us; speedup vs baseline: 1.3278x; 1.0034x over previous
//
#include <hip/hip_runtime.h>
#include <hip/hip_fp16.h>
#include <math.h>

typedef _Float16 f16;
typedef _Float16 f16x2 __attribute__((ext_vector_type(2)));
typedef _Float16 f16x4 __attribute__((ext_vector_type(4)));
typedef _Float16 f16x8 __attribute__((ext_vector_type(8)));
typedef float f32x4 __attribute__((ext_vector_type(4)));
typedef unsigned long long u64;

// async global->LDS, 16B per lane; LDS dest must be wave-uniform base (HW adds lane*16)
#define GLD16(g, s) __builtin_amdgcn_global_load_lds( \
    (const __attribute__((address_space(1))) void*)(g), \
    (__attribute__((address_space(3))) void*)(s), 16, 0, 0)

// trunc+RNE split: hi = f16(x mantissa-truncated to 13 bits) [exact cast in
// range], lo = RNE(e - em). absmax ~4e-3 measured.
struct HL { f16 h, l; };
__device__ __forceinline__ HL split1(float e) {
  float em = __uint_as_float(__float_as_uint(e) & 0xFFFFE000u);
  HL r;
  r.h = (f16)em;
  r.l = (f16)(e - em);
  return r;
}

// pair-packed UNSCALED split via v_cvt_pkrtz (A operand only: |a|<=~5.5 so
// lo ~ 2^-12|a| stays f16-normal; removing the x256 mul cuts cvt VALU 25%,
// which converts ~1:1 to wall at gemm1's 100% pipe-sum). 3 VALU/elem.
__device__ __forceinline__ void splitcvt8(f32x4 u, f32x4 v, f16x8& H, f16x8& L) {
  union { f16x2 h2[4]; f16x8 h8; } uh, ul;
#pragma unroll
  for (int p = 0; p < 2; ++p) {
    float a = u[2 * p], b = u[2 * p + 1];
    float am = __uint_as_float(__float_as_uint(a) & 0xFFFFE000u);
    float bm = __uint_as_float(__float_as_uint(b) & 0xFFFFE000u);
    auto pk = __builtin_amdgcn_cvt_pkrtz(am, bm);          // exact (normal range)
    uh.h2[p] = *reinterpret_cast<f16x2*>(&pk);
    auto pl = __builtin_amdgcn_cvt_pkrtz(a - am, b - bm);  // RTZ residual
    ul.h2[p] = *reinterpret_cast<f16x2*>(&pl);
  }
#pragma unroll
  for (int p = 0; p < 2; ++p) {
    float a = v[2 * p], b = v[2 * p + 1];
    float am = __uint_as_float(__float_as_uint(a) & 0xFFFFE000u);
    float bm = __uint_as_float(__float_as_uint(b) & 0xFFFFE000u);
    auto pk = __builtin_amdgcn_cvt_pkrtz(am, bm);
    uh.h2[2 + p] = *reinterpret_cast<f16x2*>(&pk);
    auto pl = __builtin_amdgcn_cvt_pkrtz(a - am, b - bm);
    ul.h2[2 + p] = *reinterpret_cast<f16x2*>(&pl);
  }
  H = uh.h8;
  L = ul.h8;
}

// ---------------------------------------------------------------------------
// Weight split (W6 and W7 in ONE launch, segmented by blockIdx), scale 256.
// ---------------------------------------------------------------------------
__global__ __launch_bounds__(256) void split_weights(
    const float* __restrict__ w6, f16* __restrict__ h6, f16* __restrict__ l6,
    const float* __restrict__ w7, f16* __restrict__ h7, f16* __restrict__ l7) {
  const float* src; f16* hi; f16* lo; long n4; long b0;
  if (blockIdx.x < 1024) { src = w6; hi = h6; lo = l6; n4 = 1024 * 12544 / 4; b0 = blockIdx.x; }
  else                   { src = w7; hi = h7; lo = l7; n4 = 1024 * 1024 / 4;  b0 = blockIdx.x - 1024; }
  const long nb = (blockIdx.x < 1024) ? 1024 : 256;
  long stride = nb * blockDim.x;
  for (long i = b0 * blockDim.x + threadIdx.x; i < n4; i += stride) {
    float4 v = ((const float4*)src)[i];
    f16x4 h, l;
    HL r0 = split1(v.x * 256.0f); h[0] = r0.h; l[0] = r0.l;
    HL r1 = split1(v.y * 256.0f); h[1] = r1.h; l[1] = r1.l;
    HL r2 = split1(v.z * 256.0f); h[2] = r2.h; l[2] = r2.l;
    HL r3 = split1(v.w * 256.0f); h[3] = r3.h; l[3] = r3.l;
    ((f16x4*)hi)[i] = h;
    ((f16x4*)lo)[i] = l;
  }
}

// ---------------------------------------------------------------------------
// gemm1: FUSED fp32-A split GEMM, 128x128 tile, BK=32, 4 waves (2x2),
// double-buffered LDS (64 KB -> 2 blocks/CU). A unscaled (x1), B scaled x256
// -> acc = 256*ab, epilogue /256.
// ---------------------------------------------------------------------------
__global__ __launch_bounds__(256) void gemm1_128(
    const float* __restrict__ Af,
    const f16* __restrict__ B1, const f16* __restrict__ B2,
    const float* __restrict__ bias,
    f16* __restrict__ out1, f16* __restrict__ out2,
    const int M, const int K) {
  // per buffer: A fp32 128x32 = 16K | B1 8K | B2 8K = 32 KB
  __shared__ __align__(16) char smem[2][32768];
  const int tid = threadIdx.x;           // 0..255
  const int lane = tid & 63;
  const int wid = tid >> 6;              // 0..3
  const int wr = wid >> 1, wcol = wid & 1;
  const int m0 = blockIdx.y * 128;
  const int n0 = blockIdx.x * 128;

  f32x4 acc[4][4];
#pragma unroll
  for (int m = 0; m < 4; ++m)
#pragma unroll
    for (int n = 0; n < 4; ++n) acc[m][n] = (f32x4){0.f, 0.f, 0.f, 0.f};

  // A staging (r3-verified): fp32 128x32, chunk-XOR c^(row&7)
  const float* gAf[4];
#pragma unroll
  for (int q = 0; q < 4; ++q) {
    int rowg = m0 + q * 32 + (tid >> 3);
    if (rowg > M - 1) rowg = M - 1;
    const int chunkg = (tid & 7) ^ ((tid >> 3) & 7);
    gAf[q] = Af + (size_t)rowg * K + chunkg * 4;
  }
  // B staging (r2-verified f16 pattern, 0 conflicts)
  const int rq = tid >> 2;                                  // 0..63
  const int cg = (((tid & 3) ^ ((rq >> 1) & 3)) * 8);
  const f16* gB1q0 = B1 + (size_t)(n0 + rq) * K + cg;
  const f16* gB1q1 = B1 + (size_t)(n0 + 64 + rq) * K + cg;
  const f16* gB2q0 = B2 + (size_t)(n0 + rq) * K + cg;
  const f16* gB2q1 = B2 + (size_t)(n0 + 64 + rq) * K + cg;
  const int du = wid * 512;

  const int arow = wr * 64 + (lane & 15);
  const int brow = wcol * 64 + (lane & 15);
  const int kcB = (((lane >> 4) ^ ((brow >> 1) & 3)) * 8);
  const int pA0 = (((lane >> 4) * 2)     ^ (arow & 7)) * 4;
  const int pA1 = (((lane >> 4) * 2 + 1) ^ (arow & 7)) * 4;

  const int nt = K / 32;

#define STAGE(buf, kt)                                            \
  do {                                                            \
    char* smx_ = smem[buf];                                       \
    float* db = (float*)smx_;                                     \
    GLD16(gAf[0] + (kt), db + 0 * 1024 + wid * 256);              \
    GLD16(gAf[1] + (kt), db + 1 * 1024 + wid * 256);              \
    GLD16(gAf[2] + (kt), db + 2 * 1024 + wid * 256);              \
    GLD16(gAf[3] + (kt), db + 3 * 1024 + wid * 256);              \
    GLD16(gB1q0 + (kt), (f16*)(smx_ + 16384) + du);               \
    GLD16(gB1q1 + (kt), (f16*)(smx_ + 16384) + 2048 + du);        \
    GLD16(gB2q0 + (kt), (f16*)(smx_ + 24576) + du);               \
    GLD16(gB2q1 + (kt), (f16*)(smx_ + 24576) + 2048 + du);        \
  } while (0)

  STAGE(0, 0);

  for (int t = 0; t < nt; ++t) {
    asm volatile("s_waitcnt vmcnt(0)" ::: "memory");
    asm volatile("s_waitcnt lgkmcnt(0)" ::: "memory");
    __builtin_amdgcn_s_barrier();
    __builtin_amdgcn_sched_barrier(0);

    const char* smx = smem[t & 1];
    const float* sf = (const float*)smx;
    f16x8 a1[4], a2[4], b1[4], b2[4];
#pragma unroll
    for (int m = 0; m < 4; ++m) {
      const float* rp = sf + (arow + m * 16) * 32;
      f32x4 u = *(const f32x4*)(rp + pA0);
      f32x4 v = *(const f32x4*)(rp + pA1);
      splitcvt8(u, v, a1[m], a2[m]);
    }
    {
      const f16* sb1 = (const f16*)(smx + 16384);
      const f16* sb2 = (const f16*)(smx + 24576);
#pragma unroll
      for (int n = 0; n < 4; ++n) {
        b1[n] = *(const f16x8*)&sb1[(brow + n * 16) * 32 + kcB];
        b2[n] = *(const f16x8*)&sb2[(brow + n * 16) * 32 + kcB];
      }
    }

    if (t + 1 < nt) STAGE((t + 1) & 1, (t + 1) * 32);  // after reads of this buf

    // product-major: 16 independent MFMAs between dependent acc reuses
#pragma unroll
    for (int m = 0; m < 4; ++m)
#pragma unroll
      for (int n = 0; n < 4; ++n)
        acc[m][n] = __builtin_amdgcn_mfma_f32_16x16x32_f16(a1[m], b1[n], acc[m][n], 0, 0, 0);
#pragma unroll
    for (int m = 0; m < 4; ++m)
#pragma unroll
      for (int n = 0; n < 4; ++n)
        acc[m][n] = __builtin_amdgcn_mfma_f32_16x16x32_f16(a2[m], b1[n], acc[m][n], 0, 0, 0);
#pragma unroll
    for (int m = 0; m < 4; ++m)
#pragma unroll
      for (int n = 0; n < 4; ++n)
        acc[m][n] = __builtin_amdgcn_mfma_f32_16x16x32_f16(a1[m], b2[n], acc[m][n], 0, 0, 0);
  }
#undef STAGE

  const int crow = m0 + wr * 64 + 4 * (lane >> 4);
  const int ccol0 = n0 + wcol * 64 + (lane & 15);
#pragma unroll
  for (int n = 0; n < 4; ++n) {
    const int col = ccol0 + n * 16;
    const float bv = bias[col];
#pragma unroll
    for (int m = 0; m < 4; ++m) {
#pragma unroll
      for (int j = 0; j < 4; ++j) {
        const int row = crow + m * 16 + j;
        if (row < M) {
          float v = acc[m][n][j] * (1.0f / 256.0f) + bv;   // A x1, B x256
          v = fmaxf(v, 0.0f);
          HL r = split1(v * 256.0f);
          out1[(size_t)row * 1024 + col] = r.h;
          out2[(size_t)row * 1024 + col] = r.l;
        }
      }
    }
  }
}

// ---------------------------------------------------------------------------
// gemm2: pre-split f16 hi/lo GEMM (r12 path, 256x128 tile, tbuf, vmcnt(6)).
// Both operands x256 -> /65536 epilogue.
// ---------------------------------------------------------------------------
__global__ __launch_bounds__(512) void gemm2_k(
    const f16* __restrict__ A1, const f16* __restrict__ A2,
    const f16* __restrict__ B1, const f16* __restrict__ B2,
    const float* __restrict__ bias,
    float* __restrict__ out1,
    const int M, const int K) {
  __shared__ __align__(16) char smem[3][49152];
  const int tid = threadIdx.x;
  const int lane = tid & 63;
  const int wid = tid >> 6;
  const int wr = wid >> 1, wcol = wid & 1;
  const int m0 = blockIdx.y * 256;
  const int n0 = blockIdx.x * 128;

  f32x4 acc[4][4];
#pragma unroll
  for (int m = 0; m < 4; ++m)
#pragma unroll
    for (int n = 0; n < 4; ++n) acc[m][n] = (f32x4){0.f, 0.f, 0.f, 0.f};

  const int cg = (((tid & 3) ^ ((tid >> 3) & 3)) * 8);
  const f16* gB1 = B1 + (size_t)(n0 + (tid >> 2)) * K + cg;
  const f16* gB2 = B2 + (size_t)(n0 + (tid >> 2)) * K + cg;
  int ra0 = m0 + (tid >> 2);       if (ra0 > M - 1) ra0 = M - 1;
  int ra1 = m0 + 128 + (tid >> 2); if (ra1 > M - 1) ra1 = M - 1;
  const f16* gA1q0 = A1 + (size_t)ra0 * K + cg;
  const f16* gA1q1 = A1 + (size_t)ra1 * K + cg;
  const f16* gA2q0 = A2 + (size_t)ra0 * K + cg;
  const f16* gA2q1 = A2 + (size_t)ra1 * K + cg;

  const int arow = wr * 64 + (lane & 15);
  const int brow = wcol * 64 + (lane & 15);
  const int kcA = (((lane >> 4) ^ ((arow >> 1) & 3)) * 8);
  const int kcB = (((lane >> 4) ^ ((brow >> 1) & 3)) * 8);

  const int nt = K / 32;

#define STAGE(buf, kt)                                            \
  do {                                                            \
    char* smx_ = smem[buf];                                       \
    f16* d1 = (f16*)smx_;                                         \
    f16* d2 = d1 + 8192;                                          \
    GLD16(gA1q0 + (kt), d1 + wid * 512);                          \
    GLD16(gA1q1 + (kt), d1 + 4096 + wid * 512);                   \
    GLD16(gA2q0 + (kt), d2 + wid * 512);                          \
    GLD16(gA2q1 + (kt), d2 + 4096 + wid * 512);                   \
    GLD16(gB1 + (kt), (f16*)(smx_ + 32768) + wid * 512);          \
    GLD16(gB2 + (kt), (f16*)(smx_ + 40960) + wid * 512);          \
  } while (0)

  STAGE(0, 0);
  if (nt > 1) STAGE(1, 32);
  int cur = 0;

  for (int t = 0; t < nt; ++t) {
    if (t + 1 < nt) asm volatile("s_waitcnt vmcnt(6)" ::: "memory");
    else            asm volatile("s_waitcnt vmcnt(0)" ::: "memory");
    asm volatile("s_waitcnt lgkmcnt(0)" ::: "memory");
    __builtin_amdgcn_s_barrier();
    __builtin_amdgcn_sched_barrier(0);

    const char* smx = smem[cur];
    const f16* s1 = (const f16*)smx;
    const f16* s2 = s1 + 8192;
    const f16* sb1 = (const f16*)(smx + 32768);
    const f16* sb2 = (const f16*)(smx + 40960);
    f16x8 a1[4], a2[4], b1[4], b2[4];
#pragma unroll
    for (int m = 0; m < 4; ++m) {
      a1[m] = *(const f16x8*)&s1[(arow + m * 16) * 32 + kcA];
      a2[m] = *(const f16x8*)&s2[(arow + m * 16) * 32 + kcA];
    }
#pragma unroll
    for (int n = 0; n < 4; ++n) {
      b1[n] = *(const f16x8*)&sb1[(brow + n * 16) * 32 + kcB];
      b2[n] = *(const f16x8*)&sb2[(brow + n * 16) * 32 + kcB];
    }

    int pre = cur + 2; if (pre >= 3) pre -= 3;
    if (t + 2 < nt) STAGE(pre, (t + 2) * 32);

#pragma unroll
    for (int m = 0; m < 4; ++m)
#pragma unroll
      for (int n = 0; n < 4; ++n)
        acc[m][n] = __builtin_amdgcn_mfma_f32_16x16x32_f16(a1[m], b1[n], acc[m][n], 0, 0, 0);
#pragma unroll
    for (int m = 0; m < 4; ++m)
#pragma unroll
      for (int n = 0; n < 4; ++n)
        acc[m][n] = __builtin_amdgcn_mfma_f32_16x16x32_f16(a2[m], b1[n], acc[m][n], 0, 0, 0);
#pragma unroll
    for (int m = 0; m < 4; ++m)
#pragma unroll
      for (int n = 0; n < 4; ++n)
        acc[m][n] = __builtin_amdgcn_mfma_f32_16x16x32_f16(a1[m], b2[n], acc[m][n], 0, 0, 0);

    ++cur; if (cur >= 3) cur = 0;
  }
#undef STAGE

  const int crow = m0 + wr * 64 + 4 * (lane >> 4);
  const int ccol0 = n0 + wcol * 64 + (lane & 15);
#pragma unroll
  for (int n = 0; n < 4; ++n) {
    const int col = ccol0 + n * 16;
    const float bv = bias[col];
#pragma unroll
    for (int m = 0; m < 4; ++m) {
#pragma unroll
      for (int j = 0; j < 4; ++j) {
        const int row = crow + m * 16 + j;
        if (row < M) {
          float v = acc[m][n][j] * (1.0f / 65536.0f) + bv;
          out1[(size_t)row * 1024 + col] = fmaxf(v, 0.0f);
        }
      }
    }
  }
}

// ---------------------------------------------------------------------------
// Final head: c/r dots (fp32), argmax/scores, per-class delta, box decode+clip
// ---------------------------------------------------------------------------
__device__ __forceinline__ float dot4f(float4 a, float4 b) {
  return a.x * b.x + a.y * b.y + a.z * b.z + a.w * b.w;
}

__global__ __launch_bounds__(256) void head_final(
    const float* __restrict__ v7,
    const float* __restrict__ wc, const float* __restrict__ bc,
    const float* __restrict__ wr, const float* __restrict__ br,
    const float* __restrict__ rois,
    float* __restrict__ outScores, float* __restrict__ outClasses,
    float* __restrict__ outBoxes,
    float* __restrict__ smask, float* __restrict__ wsbox, int* __restrict__ wsval) {
  const int gw = (blockIdx.x * 256 + threadIdx.x) >> 6;
  const int lane = threadIdx.x & 63;
  if (gw >= 8000) return;

  const float4* vr = (const float4*)(v7 + (size_t)gw * 1024);
  float4 x0 = vr[lane], x1 = vr[64 + lane], x2 = vr[128 + lane], x3 = vr[192 + lane];

  float s[20];
#pragma unroll
  for (int o = 0; o < 20; ++o) {
    const float* wrow = (o < 4) ? (wc + o * 1024) : (wr + (o - 4) * 1024);
    const float4* w4 = (const float4*)wrow;
    float a = dot4f(x0, w4[lane]) + dot4f(x1, w4[64 + lane]) +
              dot4f(x2, w4[128 + lane]) + dot4f(x3, w4[192 + lane]);
#pragma unroll
    for (int off = 32; off >= 1; off >>= 1) a += __shfl_xor(a, off);
    s[o] = a + ((o < 4) ? bc[o] : br[o - 4]);
  }

  float best = s[0]; int cls = 0;
  if (s[1] > best) { best = s[1]; cls = 1; }
  if (s[2] > best) { best = s[2]; cls = 2; }
  if (s[3] > best) { best = s[3]; cls = 3; }

  float d0, d1, d2, d3;  // constant indices only (avoid scratch)
  if      (cls == 0) { d0 = s[4];  d1 = s[5];  d2 = s[6];  d3 = s[7];  }
  else if (cls == 1) { d0 = s[8];  d1 = s[9];  d2 = s[10]; d3 = s[11]; }
  else if (cls == 2) { d0 = s[12]; d1 = s[13]; d2 = s[14]; d3 = s[15]; }
  else               { d0 = s[16]; d1 = s[17]; d2 = s[18]; d3 = s[19]; }

  float4 rb = ((const float4*)rois)[gw];
  float w = rb.z - rb.x, h = rb.w - rb.y;
  float cx = rb.x + 0.5f * w, cy = rb.y + 0.5f * h;
  float pcx = cx + d0 * 0.1f * w;
  float pcy = cy + d1 * 0.1f * h;
  float pw = expf(d2 * 0.2f) * w;
  float ph = expf(d3 * 0.2f) * h;
  float bx0 = fminf(fmaxf(pcx - 0.5f * pw, 0.f), 512.f);
  float by0 = fminf(fmaxf(pcy - 0.5f * ph, 0.f), 512.f);
  float bx1 = fminf(fmaxf(pcx + 0.5f * pw, 0.f), 512.f);
  float by1 = fminf(fmaxf(pcy + 0.5f * ph, 0.f), 512.f);

  if (lane == 0) {
    outScores[gw] = best;
    outClasses[gw] = (float)cls;
    outBoxes[gw * 4 + 0] = bx0;
    outBoxes[gw * 4 + 1] = by0;
    outBoxes[gw * 4 + 2] = bx1;
    outBoxes[gw * 4 + 3] = by1;
    int valid = (cls != 3);
    smask[gw] = valid ? best : -INFINITY;
    wsval[gw] = valid;
    float4 bb; bb.x = bx0; bb.y = by0; bb.z = bx1; bb.w = by1;
    ((float4*)wsbox)[gw] = bb;
  }
}

// ---------------------------------------------------------------------------
// Stable descending rank, ONE WAVE PER ROW i (r16-verified, -200us).
// ---------------------------------------------------------------------------
__global__ __launch_bounds__(256) void rank_kernel(
    const float* __restrict__ smask, const float* __restrict__ bx,
    const int* __restrict__ valid,
    int* __restrict__ order, float* __restrict__ sboxes, int* __restrict__ svalid) {
  __shared__ __align__(16) float sS[8000];
  const int tid = threadIdx.x;
  for (int i = tid; i < 2000; i += 256)
    ((float4*)sS)[i] = ((const float4*)smask)[i];
  __syncthreads();
  const int i = blockIdx.x * 4 + (tid >> 6);   // this wave's row
  const int lane = tid & 63;
  const float si = sS[i];
  int cnt = 0;
#pragma unroll 5
  for (int k = 0; k < 125; ++k) {
    const int j = k * 64 + lane;
    const float sj = sS[j];
    cnt += (sj > si) || (sj == si && j < i);
  }
#pragma unroll
  for (int off = 32; off >= 1; off >>= 1) cnt += __shfl_xor(cnt, off);
  if (lane == 0) {
    order[cnt] = i;
    svalid[cnt] = valid[i];
    ((float4*)sboxes)[cnt] = ((const float4*)bx)[i];
  }
}

// ---------------------------------------------------------------------------
// Suppression bitmask matrix, ROW-MAJOR M[ri*128+w] (coalesced OR-phase
// reads). One (t,w) per wave, 4 waves/block.
// ---------------------------------------------------------------------------
__global__ __launch_bounds__(256) void iou_matrix(const float* __restrict__ sboxes,
                                                  u64* __restrict__ M,
                                                  u64* __restrict__ Mdiag,
                                                  const int* __restrict__ svalid) {
  const int t = blockIdx.y;
  const int w = blockIdx.x * 4 + (threadIdx.x >> 6);
  if (w < t || w >= 125) return;
  if (svalid[t * 64] == 0 || svalid[w * 64] == 0) return;
  const int lane = threadIdx.x & 63;
  const int ri = t * 64 + lane;
  float4 rb = ((const float4*)sboxes)[ri];
  const float ra = (rb.z - rb.x) * (rb.w - rb.y);
  const float4* cb = (const float4*)sboxes + w * 64;
  u64 bits = 0;
#pragma unroll 4
  for (int j = 0; j < 64; ++j) {
    float4 c = cb[j];
    float x1 = fmaxf(rb.x, c.x), y1 = fmaxf(rb.y, c.y);
    float x2 = fminf(rb.z, c.z), y2 = fminf(rb.w, c.w);
    float inter = fmaxf(x2 - x1, 0.f) * fmaxf(y2 - y1, 0.f);
    float ca = (c.z - c.x) * (c.w - c.y);
    float iou = inter / (ra + ca - inter + 1e-8f);
    int gc = w * 64 + j;
    if (iou > 0.2f && gc > ri) bits |= (1ULL << j);
  }
  M[(size_t)ri * 128 + w] = bits;
  if (w == t) Mdiag[(size_t)t * 64 + lane] = bits;
}

// ---------------------------------------------------------------------------
// Sequential greedy NMS scan (r14/r16-verified). Mdiag in LDS, ctz closure,
// klist + batch-16 OR over row-major M.
// ---------------------------------------------------------------------------
__global__ __launch_bounds__(128) void nms_scan(
    const u64* __restrict__ M, const u64* __restrict__ Mdiag,
    const int* __restrict__ order,
    const int* __restrict__ svalid, float* __restrict__ outKeep) {
  __shared__ __align__(16) u64 sMdiag[8000];   // 64 KB: 125 tiles x 64 rows
  __shared__ u64 acc[126];
  __shared__ unsigned char klist[64];
  __shared__ int kcount;
  __shared__ int tv[125];
  __shared__ int nvt_s;
  const int tid = threadIdx.x;
  for (int i = tid; i < 4000; i += 128)
    ((float4*)sMdiag)[i] = ((const float4*)Mdiag)[i];
  for (int w = tid; w < 125; w += 128) acc[w] = 0;
  if (tid < 125) tv[tid] = svalid[tid * 64];
  __syncthreads();
  if (tid == 0) {
    int c = 0;
    while (c < 125 && tv[c]) ++c;
    nvt_s = c;
  }
  __syncthreads();
  const int nvt = nvt_s;

  for (int t = 0; t < nvt; ++t) {
    if (tid < 64) {  // wave 0: ctz closure over kept boxes
      u64 myrow = sMdiag[t * 64 + tid];
      unsigned mlo = (unsigned)myrow, mhi = (unsigned)(myrow >> 32);
      u64 r = acc[t];
      u64 rem = ~r;                       // surviving candidates
      while (rem) {
        int i = __builtin_ctzll(rem);     // next kept box
        unsigned rlo = (unsigned)__builtin_amdgcn_readlane((int)mlo, i);
        unsigned rhi = (unsigned)__builtin_amdgcn_readlane((int)mhi, i);
        u64 rowi = ((u64)rhi << 32) | (u64)rlo;
        r |= rowi;
        rem &= ~(rowi | (1ULL << i));
      }
      u64 kept = ~r;
      if (tid == 0) { acc[t] = r; kcount = (int)__popcll(kept); }
      if ((kept >> tid) & 1ULL)
        klist[__popcll(kept & ((1ULL << tid) - 1ULL))] = (unsigned char)tid;
    }
    __syncthreads();
    const int kc = kcount;
    const int w = t + 1 + tid;
    if (w < nvt) {
      u64 a = acc[w];
      const u64* base = M + (size_t)t * 64 * 128 + w;
      int j = 0;
      for (; j + 16 <= kc; j += 16) {   // 16 outstanding loads
        u64 o = 0;
#pragma unroll
        for (int q = 0; q < 16; ++q) o |= base[(size_t)klist[j + q] * 128];
        a |= o;
      }
      for (; j + 4 <= kc; j += 4) {
        u64 v0 = base[(size_t)klist[j] * 128];
        u64 v1 = base[(size_t)klist[j + 1] * 128];
        u64 v2 = base[(size_t)klist[j + 2] * 128];
        u64 v3 = base[(size_t)klist[j + 3] * 128];
        a |= (v0 | v1) | (v2 | v3);
      }
      for (; j < kc; ++j) a |= base[(size_t)klist[j] * 128];
      acc[w] = a;
    }
    __syncthreads();
  }

  for (int p = tid; p < 8000; p += 128) {
    int removed = (int)((acc[p >> 6] >> (p & 63)) & 1ULL);
    float kv = (!removed && svalid[p]) ? 1.0f : 0.0f;
    outKeep[order[p]] = kv;
  }
}

// ---------------------------------------------------------------------------
extern "C" void kernel_launch(void* const* d_in, const int* in_sizes, int n_in,
                              void* d_out, int out_size, void* d_ws, size_t ws_size,
                              hipStream_t stream) {
  const float* F    = (const float*)d_in[0];
  const float* ROIS = (const float*)d_in[1];
  const float* W6   = (const float*)d_in[2];
  const float* B6   = (const float*)d_in[3];
  const float* W7   = (const float*)d_in[4];
  const float* B7   = (const float*)d_in[5];
  const float* WC   = (const float*)d_in[6];
  const float* BC   = (const float*)d_in[7];
  const float* WR   = (const float*)d_in[8];
  const float* BR   = (const float*)d_in[9];

  const size_t N = 8000, D = 12544, H = 1024;
  char* ws = (char*)d_ws;
  size_t off = 0;
  auto alloc = [&](size_t bytes) -> void* {
    void* p = (void*)(ws + off);
    off += (bytes + 255) & ~(size_t)255;
    return p;
  };
  f16*   B1w   = (f16*)alloc(H * D * 2);
  f16*   B2w   = (f16*)alloc(H * D * 2);
  f16*   V61   = (f16*)alloc(N * H * 2);
  f16*   V62   = (f16*)alloc(N * H * 2);
  f16*   W71   = (f16*)alloc(H * H * 2);
  f16*   W72   = (f16*)alloc(H * H * 2);
  float* V7    = (float*)alloc(N * H * 4);
  float* SMASK = (float*)alloc(N * 4);
  float* WSBOX = (float*)alloc(N * 16);
  int*   WSVAL = (int*)alloc(N * 4);
  int*   ORDER = (int*)alloc(N * 4);
  float* SBOX  = (float*)alloc(N * 16);
  int*   SVAL  = (int*)alloc(N * 4);
  u64*   MM    = (u64*)alloc(N * 128 * 8);
  u64*   MDIAG = (u64*)alloc(125 * 64 * 8);

  float* outScores  = (float*)d_out;
  float* outClasses = (float*)d_out + 8000;
  float* outBoxes   = (float*)d_out + 16000;
  float* outKeep    = (float*)d_out + 48000;

  split_weights<<<1280, 256, 0, stream>>>(W6, B1w, B2w, W7, W71, W72);

  gemm1_128<<<dim3(8, 63), 256, 0, stream>>>(F, B1w, B2w, B6, V61, V62, 8000, 12544);
  gemm2_k<<<dim3(8, 32), 512, 0, stream>>>(V61, V62, W71, W72, B7, V7, 8000, 1024);

  head_final<<<2000, 256, 0, stream>>>(V7, WC, BC, WR, BR, ROIS,
                                       outScores, outClasses, outBoxes,
                                       SMASK, WSBOX, WSVAL);
  rank_kernel<<<2000, 256, 0, stream>>>(SMASK, WSBOX, WSVAL, ORDER, SBOX, SVAL);
  iou_matrix<<<dim3(32, 125), 256, 0, stream>>>(SBOX, MM, MDIAG, SVAL);
  nms_scan<<<1, 128, 0, stream>>>(MM, MDIAG, ORDER, SVAL, outKeep);
}